// Round 3
// baseline (27460.922 us; speedup 1.0000x reference)
//
#include <hip/hip_runtime.h>
#include <math.h>

#define Bn   128
#define Sn   336
#define INd  64
#define Hn   1024
#define Tn   96
#define G4   4096
#define KENC 1088   // 64 + 1024 = 34*32
#define KDEC 2080   // 1 + 1024 + 1024 + 31 pad = 65*32
#define KQ   1024
#define NBLK 256    // persistent encoder blocks

typedef __attribute__((ext_vector_type(8))) short short8;
typedef __attribute__((ext_vector_type(4))) float floatx4;

__device__ __forceinline__ float sigmoidf_(float x){ return 1.0f/(1.0f+expf(-x)); }

__device__ __forceinline__ unsigned short f2bf(float f){
    union { float f; unsigned u; } v; v.f = f;
    unsigned r = v.u + 0x7fffu + ((v.u >> 16) & 1u);
    return (unsigned short)(r >> 16);
}
__device__ __forceinline__ float bflo(unsigned u){ union{unsigned u; float f;} v; v.u = u << 16;        return v.f; }
__device__ __forceinline__ float bfhi(unsigned u){ union{unsigned u; float f;} v; v.u = u & 0xffff0000u; return v.f; }

__device__ __forceinline__ void gload16(const void* g, void* l){
    __builtin_amdgcn_global_load_lds((const __attribute__((address_space(1))) void*)g,
                                     (__attribute__((address_space(3))) void*)l, 16, 0, 0);
}

// =================== packing ===============================================
// Encoder weights in per-block MFMA-fragment order:
// Wp[ug][kc][lane][8] ; lane: n = lane&15 (gate = n>>2, u' = n&3), kg = lane>>4
// unit = ug*4 + u', orig row = gate*Hn + unit, k = kc*32 + kg*8 + j
__global__ void pack_enc2(const float* __restrict__ Wih, const float* __restrict__ Whh,
                          const float* __restrict__ bih, const float* __restrict__ bhh,
                          unsigned short* __restrict__ Wp, float* __restrict__ bc){
    long n = (long)NBLK*34*512;
    for (long idx = (long)blockIdx.x*256 + threadIdx.x; idx < n; idx += (long)gridDim.x*256){
        int j = idx & 7;
        int lane = (int)((idx >> 3) & 63);
        int kc = (int)((idx >> 9) % 34);
        int ug = (int)(idx / (34*512));
        int nn = lane & 15, kg = lane >> 4;
        int gate = nn >> 2, up = nn & 3;
        int unit = ug*4 + up;
        int k = kc*32 + kg*8 + j;
        int orig = gate*Hn + unit;
        float v = (k < INd) ? Wih[orig*INd + k] : Whh[(size_t)orig*Hn + (k - INd)];
        Wp[idx] = f2bf(v);
    }
    int tid = blockIdx.x*256 + threadIdx.x;
    if (tid < G4){
        int ug = tid >> 4, cc = tid & 15;
        int gate = cc >> 2, unit = ug*4 + (cc & 3);
        int orig = gate*Hn + unit;
        bc[tid] = bih[orig] + bhh[orig];
    }
}

__global__ void pack_dec(const float* __restrict__ Wih, const float* __restrict__ Whh,
                         const float* __restrict__ bih, const float* __restrict__ bhh,
                         unsigned short* __restrict__ Wp, float* __restrict__ bcat){
    long n = (long)G4*KDEC;
    for (long idx = (long)blockIdx.x*256 + threadIdx.x; idx < n; idx += (long)gridDim.x*256){
        int p = (int)(idx / KDEC), k = (int)(idx % KDEC);
        int g = (p >> 4) & 3, u = (p >> 6)*16 + (p & 15);
        int orig = g*Hn + u;
        float v;
        if (k <= Hn)        v = Wih[(size_t)orig*(Hn+1) + k];
        else if (k <= 2*Hn) v = Whh[(size_t)orig*Hn + (k - 1 - Hn)];
        else                v = 0.0f;
        Wp[idx] = f2bf(v);
    }
    int tid = blockIdx.x*256 + threadIdx.x;
    if (tid < G4){
        int g = (tid >> 4) & 3, u = (tid >> 6)*16 + (tid & 15);
        int orig = g*Hn + u;
        bcat[tid] = bih[orig] + bhh[orig];
    }
}

__global__ void pack_attn(const float* __restrict__ w, unsigned short* __restrict__ d){
    int n = Hn*Hn;
    for (int i = blockIdx.x*256 + threadIdx.x; i < n; i += gridDim.x*256) d[i] = f2bf(w[i]);
}

__global__ void conv_src(const float* __restrict__ s, unsigned short* __restrict__ d){
    int n = Bn*Sn*INd;
    for (int i = blockIdx.x*256 + threadIdx.x; i < n; i += gridDim.x*256) d[i] = f2bf(s[i]);
}

__global__ void init_ws(unsigned short* __restrict__ hb0, float* __restrict__ cbuf,
                        unsigned short* __restrict__ A0, unsigned short* __restrict__ A1,
                        unsigned* __restrict__ bar){
    int i = blockIdx.x*256 + threadIdx.x;
    if (i < Bn*Hn){ hb0[i] = 0; cbuf[i] = 0.0f; }
    if (i < Bn*KDEC){ A0[i] = 0; A1[i] = 0; }
    if (i < 2) bar[i] = 0;
}

// =================== device-scope grid barrier =============================
__device__ __forceinline__ void grid_barrier(unsigned* cnt, unsigned* gen){
    __threadfence();
    __syncthreads();
    if (threadIdx.x == 0){
        unsigned g = __hip_atomic_load(gen, __ATOMIC_RELAXED, __HIP_MEMORY_SCOPE_AGENT);
        unsigned arrived = __hip_atomic_fetch_add(cnt, 1u, __ATOMIC_ACQ_REL, __HIP_MEMORY_SCOPE_AGENT) + 1u;
        if (arrived == (unsigned)NBLK){
            __hip_atomic_store(cnt, 0u, __ATOMIC_RELAXED, __HIP_MEMORY_SCOPE_AGENT);
            __hip_atomic_store(gen, g + 1u, __ATOMIC_RELEASE, __HIP_MEMORY_SCOPE_AGENT);
        } else {
            while (__hip_atomic_load(gen, __ATOMIC_RELAXED, __HIP_MEMORY_SCOPE_AGENT) == g){
                __builtin_amdgcn_s_sleep(1);
            }
            (void)__hip_atomic_load(gen, __ATOMIC_ACQUIRE, __HIP_MEMORY_SCOPE_AGENT);
        }
    }
    __syncthreads();
}

// =================== persistent weight-stationary encoder ==================
// 256 blocks; block owns 16 packed W rows (4 units x 4 gates) in 136 VGPRs.
// Per step: stream A=[x_t|h] through LDS (fragment-order, groups of 4 chunks),
// 2 MFMAs/wave/chunk, LDS gate-combine epilogue, c-state in registers.
__global__ __launch_bounds__(256, 1)
void enc_persistent(const unsigned short* __restrict__ Wp, const float* __restrict__ bc,
                    const unsigned short* __restrict__ srcbf,
                    unsigned short* __restrict__ hb0, unsigned short* __restrict__ hb1,
                    unsigned short* __restrict__ enco, unsigned short* __restrict__ adec_h,
                    float* __restrict__ cbuf,
                    unsigned* __restrict__ bar)
{
    __shared__ __align__(16) char pool[65536];   // Abuf[2][4][8192]; Cs aliases buf1
    float* Cs = (float*)(pool + 32768);          // [128][17] fp32, valid only in epilogue

    const int tid = threadIdx.x;
    const int l = tid & 63;
    const int w = tid >> 6;
    // XCD swizzle: blocks on XCD x own contiguous units [x*128, (x+1)*128)
    const int ug = ((blockIdx.x & 7) << 5) | (blockIdx.x >> 3);

    // ---- one-time: weights into registers (fragment order) ----
    short8 bfr[34];
    const unsigned short* wg = Wp + (size_t)ug * (34*512) + l*8;
    #pragma unroll
    for (int kc = 0; kc < 34; kc++) bfr[kc] = *(const short8*)(wg + kc*512);

    float breg[16];
    #pragma unroll
    for (int i = 0; i < 16; i++) breg[i] = bc[ug*16 + i];

    float creg[4] = {0,0,0,0};

    unsigned short* hbuf[2] = {hb0, hb1};

    for (int t = 0; t < Sn; t++){
        const unsigned short* hin = hbuf[t & 1];
        unsigned short* hout = hbuf[(t + 1) & 1];

        // stage group g (chunks 4g..4g+3) into pool[(g&1)*32768]
        auto stage = [&](int g){
            char* sb = pool + (g & 1)*32768;
            #pragma unroll
            for (int it = 0; it < 8; it++){
                int chunkid = g*4 + (it >> 1);
                if (chunkid < 34){
                    int tc = ((it & 1) << 8) + tid;
                    int row = ((tc >> 6) << 4) | (tc & 15);   // fragment-order: msub*16 + r16
                    int ko  = ((tc >> 4) & 3) << 3;
                    int k = chunkid*32 + ko;
                    const unsigned short* gp = (chunkid < 2)
                        ? srcbf + ((size_t)row*Sn + t)*INd + k
                        : hin + (size_t)row*Hn + (k - INd);
                    gload16(gp, sb + (it >> 1)*8192 + tc*16);
                }
            }
        };

        floatx4 acc0 = {0,0,0,0}, acc1 = {0,0,0,0};
        stage(0);
        #pragma unroll
        for (int kc = 0; kc < 34; kc++){
            if ((kc & 3) == 0){
                __syncthreads();                 // staging(group kc/4) landed
                int g = kc >> 2;
                if (g < 8) stage(g + 1);
            }
            const char* ab = pool + (((kc >> 2) & 1))*32768 + (kc & 3)*8192;
            short8 a0 = *(const short8*)(ab + (w*2    )*1024 + l*16);
            short8 a1 = *(const short8*)(ab + (w*2 + 1)*1024 + l*16);
            acc0 = __builtin_amdgcn_mfma_f32_16x16x32_bf16(a0, bfr[kc], acc0, 0, 0, 0);
            acc1 = __builtin_amdgcn_mfma_f32_16x16x32_bf16(a1, bfr[kc], acc1, 0, 0, 0);
        }

        __syncthreads();   // all waves done reading LDS before Cs alias write
        {
            const int q = l >> 4, col = l & 15;
            #pragma unroll
            for (int r = 0; r < 4; r++){
                Cs[(w*32      + q*4 + r)*17 + col] = acc0[r];
                Cs[(w*32 + 16 + q*4 + r)*17 + col] = acc1[r];
            }
        }
        __syncthreads();
        if (tid < Bn){
            const int b = tid;
            float h4[4];
            #pragma unroll
            for (int up = 0; up < 4; up++){
                float gi = Cs[b*17 +      up] + breg[     up];
                float gf = Cs[b*17 +  4 + up] + breg[ 4 + up];
                float gg = Cs[b*17 +  8 + up] + breg[ 8 + up];
                float go = Cs[b*17 + 12 + up] + breg[12 + up];
                float cn = sigmoidf_(gf)*creg[up] + sigmoidf_(gi)*tanhf(gg);
                creg[up] = cn;
                h4[up] = sigmoidf_(go)*tanhf(cn);
            }
            ushort4 hv;
            hv.x = f2bf(h4[0]); hv.y = f2bf(h4[1]); hv.z = f2bf(h4[2]); hv.w = f2bf(h4[3]);
            *(ushort4*)(hout + (size_t)b*Hn + ug*4) = hv;
            *(ushort4*)(enco + ((size_t)b*Sn + t)*Hn + ug*4) = hv;
            if (t == Sn - 1){
                unsigned short* ap = adec_h + (size_t)b*KDEC + ug*4;
                ap[0] = hv.x; ap[1] = hv.y; ap[2] = hv.z; ap[3] = hv.w;
                float4 cv; cv.x = creg[0]; cv.y = creg[1]; cv.z = creg[2]; cv.w = creg[3];
                *(float4*)(cbuf + (size_t)b*Hn + ug*4) = cv;
            }
        }
        grid_barrier(bar, bar + 1);
    }
}

// =================== decoder kernels (unchanged from R2) ====================
template<int MODE, int K>   // 1=dec LSTM, 2=attn query
__global__ __launch_bounds__(256)
void mfma_gemm(const unsigned short* __restrict__ Abase,
               const unsigned short* __restrict__ W,
               const float* __restrict__ bcat,
               float* __restrict__ cst,
               unsigned short* __restrict__ hout,
               unsigned short* __restrict__ adec_h)
{
    __shared__ __align__(16) unsigned short As[64*32];
    __shared__ __align__(16) unsigned short Bs[64*32];
    const int tid = threadIdx.x;
    const int l = tid & 63;
    const int w = tid >> 6;
    const int m0 = blockIdx.x * 64;
    const int n0 = blockIdx.y * 64;

    floatx4 acc0 = {0,0,0,0}, acc1 = {0,0,0,0}, acc2 = {0,0,0,0}, acc3 = {0,0,0,0};

    const int arow = tid >> 2;
    const int kch  = (tid & 3) << 3;
    const int am   = m0 + arow;
    const unsigned short* wptr = W + (size_t)(n0 + arow) * K + kch;
    const unsigned short* aptr = Abase + (size_t)am * (MODE == 1 ? KDEC : Hn) + kch;

    void* ldsA = (void*)((char*)As + w * 1024);
    void* ldsB = (void*)((char*)Bs + w * 1024);

    const int aoff  = (w*16 + (l & 15)) * 64 + (l >> 4) * 16;
    const int boff  = (l & 15) * 64 + (l >> 4) * 16;

    for (int k0 = 0; k0 < K; k0 += 32){
        gload16(aptr + k0, ldsA);
        gload16(wptr + k0, ldsB);
        __syncthreads();
        short8 a  = *(const short8*)((const char*)As + aoff);
        short8 b0 = *(const short8*)((const char*)Bs + boff);
        short8 b1 = *(const short8*)((const char*)Bs + boff + 16*64);
        short8 b2 = *(const short8*)((const char*)Bs + boff + 32*64);
        short8 b3 = *(const short8*)((const char*)Bs + boff + 48*64);
        acc0 = __builtin_amdgcn_mfma_f32_16x16x32_bf16(a, b0, acc0, 0, 0, 0);
        acc1 = __builtin_amdgcn_mfma_f32_16x16x32_bf16(a, b1, acc1, 0, 0, 0);
        acc2 = __builtin_amdgcn_mfma_f32_16x16x32_bf16(a, b2, acc2, 0, 0, 0);
        acc3 = __builtin_amdgcn_mfma_f32_16x16x32_bf16(a, b3, acc3, 0, 0, 0);
        __syncthreads();
    }

    const int rbase = m0 + w*16 + ((l >> 4) << 2);
    const int col = l & 15;
    if (MODE == 2){
        #pragma unroll
        for (int r = 0; r < 4; r++){
            unsigned short* qp = hout + (size_t)(rbase + r) * Hn + n0 + col;
            qp[0]  = f2bf(acc0[r]);
            qp[16] = f2bf(acc1[r]);
            qp[32] = f2bf(acc2[r]);
            qp[48] = f2bf(acc3[r]);
        }
    } else {
        const int u = blockIdx.y * 16 + col;
        const float bi  = bcat[n0 + col];
        const float bf_ = bcat[n0 + 16 + col];
        const float bg  = bcat[n0 + 32 + col];
        const float bo  = bcat[n0 + 48 + col];
        #pragma unroll
        for (int r = 0; r < 4; r++){
            const int m = rbase + r;
            float gi = acc0[r] + bi;
            float gf = acc1[r] + bf_;
            float gg = acc2[r] + bg;
            float go = acc3[r] + bo;
            float co = cst[(size_t)m * Hn + u];
            float cn = sigmoidf_(gf) * co + sigmoidf_(gi) * tanhf(gg);
            float hv = sigmoidf_(go) * tanhf(cn);
            cst[(size_t)m * Hn + u] = cn;
            unsigned short hb = f2bf(hv);
            hout[(size_t)m * Hn + u] = hb;
            adec_h[(size_t)m * KDEC + u] = hb;
        }
    }
}

__global__ __launch_bounds__(256)
void energy_kernel(const unsigned short* __restrict__ q, const unsigned short* __restrict__ enc,
                   float* __restrict__ energy){
    int b = blockIdx.x;
    int wv = threadIdx.x >> 6, l = threadIdx.x & 63;
    int s = blockIdx.y*4 + wv;
    const uint4* qp = (const uint4*)(q + (size_t)b*Hn);
    const uint4* ep = (const uint4*)(enc + ((size_t)b*Sn + s)*Hn);
    float acc = 0.0f;
    #pragma unroll
    for (int i = 0; i < 2; i++){
        uint4 qv = qp[l + i*64];
        uint4 ev = ep[l + i*64];
        acc += bflo(qv.x)*bflo(ev.x) + bfhi(qv.x)*bfhi(ev.x);
        acc += bflo(qv.y)*bflo(ev.y) + bfhi(qv.y)*bfhi(ev.y);
        acc += bflo(qv.z)*bflo(ev.z) + bfhi(qv.z)*bfhi(ev.z);
        acc += bflo(qv.w)*bflo(ev.w) + bfhi(qv.w)*bfhi(ev.w);
    }
    #pragma unroll
    for (int off = 32; off; off >>= 1) acc += __shfl_down(acc, off);
    if (l == 0) energy[b*Sn + s] = acc;
}

__global__ __launch_bounds__(256)
void softmax_ctx_kernel(const float* __restrict__ energy, const unsigned short* __restrict__ enc,
                        unsigned short* __restrict__ ctx_out){
    __shared__ float wsm[Sn];
    __shared__ float red[256];
    int b = blockIdx.x, tid = threadIdx.x;
    float m = -1e30f;
    for (int s = tid; s < Sn; s += 256){ float e = energy[b*Sn + s]; wsm[s] = e; m = fmaxf(m, e); }
    red[tid] = m; __syncthreads();
    for (int o = 128; o; o >>= 1){ if (tid < o) red[tid] = fmaxf(red[tid], red[tid+o]); __syncthreads(); }
    m = red[0]; __syncthreads();
    float sum = 0.0f;
    for (int s = tid; s < Sn; s += 256){ float e = expf(wsm[s] - m); wsm[s] = e; sum += e; }
    red[tid] = sum; __syncthreads();
    for (int o = 128; o; o >>= 1){ if (tid < o) red[tid] += red[tid+o]; __syncthreads(); }
    float inv = 1.0f / red[0];
    float a0=0,a1=0,a2=0,a3=0;
    const uint2* base = (const uint2*)(enc + (size_t)b*Sn*Hn) + tid;
    #pragma unroll 4
    for (int s = 0; s < Sn; s++){
        float wv = wsm[s] * inv;
        uint2 v = base[(size_t)s*256];
        a0 += wv*bflo(v.x); a1 += wv*bfhi(v.x);
        a2 += wv*bflo(v.y); a3 += wv*bfhi(v.y);
    }
    unsigned short* cp = ctx_out + (size_t)b*KDEC + tid*4;
    cp[0] = f2bf(a0); cp[1] = f2bf(a1); cp[2] = f2bf(a2); cp[3] = f2bf(a3);
}

__global__ __launch_bounds__(256)
void fc_out_kernel(const unsigned short* __restrict__ h, const float* __restrict__ fcW,
                   const float* __restrict__ fcb, float* __restrict__ out,
                   unsigned short* __restrict__ prevy_slot, int d){
    __shared__ float red[256];
    int b = blockIdx.x, tid = threadIdx.x;
    uint2 v = ((const uint2*)(h + (size_t)b*Hn))[tid];
    float acc = fcW[tid*4+0]*bflo(v.x) + fcW[tid*4+1]*bfhi(v.x)
              + fcW[tid*4+2]*bflo(v.y) + fcW[tid*4+3]*bfhi(v.y);
    red[tid] = acc; __syncthreads();
    for (int o = 128; o; o >>= 1){ if (tid < o) red[tid] += red[tid+o]; __syncthreads(); }
    if (tid == 0){
        float p = red[0] + fcb[0];
        out[b*Tn + d] = p;
        prevy_slot[(size_t)b*KDEC] = f2bf(p);
    }
}

extern "C" void kernel_launch(void* const* d_in, const int* in_sizes, int n_in,
                              void* d_out, int out_size, void* d_ws, size_t ws_size,
                              hipStream_t stream){
    const float* src  = (const float*)d_in[0];
    const float* eWih = (const float*)d_in[1];
    const float* eWhh = (const float*)d_in[2];
    const float* ebih = (const float*)d_in[3];
    const float* ebhh = (const float*)d_in[4];
    const float* dWih = (const float*)d_in[5];
    const float* dWhh = (const float*)d_in[6];
    const float* dbih = (const float*)d_in[7];
    const float* dbhh = (const float*)d_in[8];
    const float* attnW= (const float*)d_in[9];
    const float* fcW  = (const float*)d_in[10];
    const float* fcb  = (const float*)d_in[11];
    float* out = (float*)d_out;

    char* base = (char*)d_ws;
    auto alloc = [&](size_t bytes){ void* p = base; base += (bytes + 255) & ~255ull; return p; };
    unsigned short* Wenc2 = (unsigned short*)alloc((size_t)NBLK*34*512*2);
    float*          benc2 = (float*)alloc(G4*4);
    unsigned short* Wdec  = (unsigned short*)alloc((size_t)G4*KDEC*2);
    float*          bdec  = (float*)alloc(G4*4);
    unsigned short* Wattn = (unsigned short*)alloc((size_t)Hn*Hn*2);
    unsigned short* srcbf = (unsigned short*)alloc((size_t)Bn*Sn*INd*2);
    unsigned short* enco  = (unsigned short*)alloc((size_t)Bn*Sn*Hn*2);
    unsigned short* hb0   = (unsigned short*)alloc((size_t)Bn*Hn*2);
    unsigned short* hb1   = (unsigned short*)alloc((size_t)Bn*Hn*2);
    float*          cbuf  = (float*)alloc((size_t)Bn*Hn*4);
    unsigned short* A0    = (unsigned short*)alloc((size_t)Bn*KDEC*2);
    unsigned short* A1    = (unsigned short*)alloc((size_t)Bn*KDEC*2);
    unsigned short* qbf   = (unsigned short*)alloc((size_t)Bn*Hn*2);
    float*          ener  = (float*)alloc((size_t)Bn*Sn*4);
    unsigned*       bar   = (unsigned*)alloc(256);

    conv_src<<<4096, 256, 0, stream>>>(src, srcbf);
    pack_enc2<<<4096, 256, 0, stream>>>(eWih, eWhh, ebih, ebhh, Wenc2, benc2);
    pack_dec<<<8192, 256, 0, stream>>>(dWih, dWhh, dbih, dbhh, Wdec, bdec);
    pack_attn<<<2048, 256, 0, stream>>>(attnW, Wattn);
    init_ws<<<1040, 256, 0, stream>>>(hb0, cbuf, A0, A1, bar);

    // ---- persistent encoder: 336 steps, one launch ----
    enc_persistent<<<NBLK, 256, 0, stream>>>(Wenc2, benc2, srcbf, hb0, hb1,
                                             enco, A0 + 1025, cbuf, bar);

    unsigned short* hb[2] = {hb0, hb1};
    unsigned short* Ad[2] = {A0, A1};
    dim3 blk(256);
    dim3 gl(2, 64);
    dim3 gq(2, 16);

    for (int d = 0; d < Tn; d++){
        unsigned short* hc = hb[d&1];
        unsigned short* hn = hb[(d+1)&1];
        unsigned short* Ac = Ad[d&1];
        unsigned short* An = Ad[(d+1)&1];
        mfma_gemm<2, KQ><<<gq, blk, 0, stream>>>(hc, Wattn, nullptr, nullptr, qbf, nullptr);
        energy_kernel<<<dim3(Bn, 84), blk, 0, stream>>>(qbf, enco, ener);
        softmax_ctx_kernel<<<Bn, blk, 0, stream>>>(ener, enco, Ac + 1);
        mfma_gemm<1, KDEC><<<gl, blk, 0, stream>>>(Ac, Wdec, bdec, cbuf, hn, An + 1025);
        fc_out_kernel<<<Bn, blk, 0, stream>>>(hn, fcW, fcb, out, An, d);
    }
}

// Round 4
// 11927.032 us; speedup vs baseline: 2.3024x; 2.3024x over previous
//
#include <hip/hip_runtime.h>
#include <math.h>

#define Bn   128
#define Sn   336
#define INd  64
#define Hn   1024
#define Tn   96
#define G4   4096
#define KCE  34     // enc k-chunks: [x(64) | h(1024)] = 2 + 32
#define KCD  65     // dec k-chunks: [ctx(1024) | h(1024) | prev_y(1) | pad] = 32+32+1
#define KCQ  32     // attn query k-chunks

typedef __attribute__((ext_vector_type(8))) short short8;
typedef __attribute__((ext_vector_type(4))) float floatx4;

__device__ __forceinline__ float sigmoidf_(float x){ return 1.0f/(1.0f+expf(-x)); }

__device__ __forceinline__ unsigned short f2bf(float f){
    union { float f; unsigned u; } v; v.f = f;
    unsigned r = v.u + 0x7fffu + ((v.u >> 16) & 1u);
    return (unsigned short)(r >> 16);
}
__device__ __forceinline__ float bflo(unsigned u){ union{unsigned u; float f;} v; v.u = u << 16;        return v.f; }
__device__ __forceinline__ float bfhi(unsigned u){ union{unsigned u; float f;} v; v.u = u & 0xffff0000u; return v.f; }

// ===================== fragment-order packing ==============================
// B-fragment for subtile s, chunk kc: [s][kc][lane(64)][8];
// lane l: col c = l&15, k = kc*32 + (l>>4)*8 + j.
// LSTM swizzle: subtile s -> gate = s&3, unit = (s>>2)*16 + c.
__global__ void pack_encf(const float* __restrict__ Wih, const float* __restrict__ Whh,
                          const float* __restrict__ bih, const float* __restrict__ bhh,
                          unsigned short* __restrict__ Wp, float* __restrict__ bc){
    long n = (long)256*KCE*512;
    for (long idx = (long)blockIdx.x*256 + threadIdx.x; idx < n; idx += (long)gridDim.x*256){
        int j = (int)(idx & 7), l = (int)((idx >> 3) & 63);
        int kc = (int)((idx >> 9) % KCE);
        int s  = (int)(idx / (KCE*512));
        int c = l & 15, kg = l >> 4;
        int k = kc*32 + kg*8 + j;
        int gate = s & 3, unit = (s >> 2)*16 + c;
        int orig = gate*Hn + unit;
        float v = (k < INd) ? Wih[orig*INd + k] : Whh[(size_t)orig*Hn + (k - INd)];
        Wp[idx] = f2bf(v);
    }
    int tid = blockIdx.x*256 + threadIdx.x;
    if (tid < G4){
        int g = (tid >> 4) & 3, u = (tid >> 6)*16 + (tid & 15);
        int orig = g*Hn + u;
        bc[tid] = bih[orig] + bhh[orig];
    }
}

__global__ void pack_decf(const float* __restrict__ Wih, const float* __restrict__ Whh,
                          const float* __restrict__ bih, const float* __restrict__ bhh,
                          unsigned short* __restrict__ Wp, float* __restrict__ bc){
    long n = (long)256*KCD*512;
    for (long idx = (long)blockIdx.x*256 + threadIdx.x; idx < n; idx += (long)gridDim.x*256){
        int j = (int)(idx & 7), l = (int)((idx >> 3) & 63);
        int kc = (int)((idx >> 9) % KCD);
        int s  = (int)(idx / (KCD*512));
        int c = l & 15, kg = l >> 4;
        int k = kc*32 + kg*8 + j;
        int gate = s & 3, unit = (s >> 2)*16 + c;
        int orig = gate*Hn + unit;
        float v;
        if (k < Hn)          v = Wih[(size_t)orig*(Hn+1) + 1 + k];     // ctx
        else if (k < 2*Hn)   v = Whh[(size_t)orig*Hn + (k - Hn)];      // h
        else if (k == 2*Hn)  v = Wih[(size_t)orig*(Hn+1)];             // prev_y
        else                 v = 0.0f;                                  // pad
        Wp[idx] = f2bf(v);
    }
    int tid = blockIdx.x*256 + threadIdx.x;
    if (tid < G4){
        int g = (tid >> 4) & 3, u = (tid >> 6)*16 + (tid & 15);
        int orig = g*Hn + u;
        bc[tid] = bih[orig] + bhh[orig];
    }
}

__global__ void pack_attnf(const float* __restrict__ w, unsigned short* __restrict__ Wp){
    int n = 64*KCQ*512;
    for (int idx = blockIdx.x*256 + threadIdx.x; idx < n; idx += gridDim.x*256){
        int j = idx & 7, l = (idx >> 3) & 63;
        int kc = (idx >> 9) & 31;
        int s  = idx >> 14;
        int nn = s*16 + (l & 15);
        int k = kc*32 + (l >> 4)*8 + j;
        Wp[idx] = f2bf(w[(size_t)nn*Hn + k]);
    }
}

// A-fragment for src: [t][rg(8)][kc(2)][lane][8]; row b = rg*16 + (l&15)
__global__ void conv_srcf(const float* __restrict__ s, unsigned short* __restrict__ d){
    int n = Sn*8*2*512;
    for (int idx = blockIdx.x*256 + threadIdx.x; idx < n; idx += gridDim.x*256){
        int j = idx & 7, l = (idx >> 3) & 63;
        int kc = (idx >> 9) & 1, rg = (idx >> 10) & 7, t = idx >> 13;
        int b = rg*16 + (l & 15);
        int k = kc*32 + (l >> 4)*8 + j;
        d[idx] = f2bf(s[((size_t)b*Sn + t)*INd + k]);
    }
}

__global__ void init_ws(unsigned short* __restrict__ hf0, float* __restrict__ cbuf,
                        unsigned short* __restrict__ A0, unsigned short* __restrict__ A1){
    for (int i = blockIdx.x*256 + threadIdx.x; i < 8*KCD*512; i += gridDim.x*256){
        A0[i] = 0; A1[i] = 0;
        if (i < 8*32*512) hf0[i] = 0;
        if (i < Bn*Hn) cbuf[i] = 0.0f;
    }
}

// ===================== encoder step: direct-fragment, no barriers ==========
// grid (4, 64), block 128 (2 waves). Wave: rows rg*16..+15, subtiles 4y..4y+3
// (= gates i,f,g,o of units y*16..+15). All loads lane-contiguous dwordx4.
__global__ __launch_bounds__(128)
void enc_step(const unsigned short* __restrict__ srcfrag,  // [336][8][2][512]
              const unsigned short* __restrict__ hin,      // [8][32][512]
              const unsigned short* __restrict__ Wf,       // [256][KCE][512]
              const float* __restrict__ bc, float* __restrict__ cbuf,
              unsigned short* __restrict__ hout,           // [8][32][512]
              unsigned short* __restrict__ enco,
              unsigned short* __restrict__ adec0,          // [8][KCD][512]
              int t, int last)
{
    const int tid = threadIdx.x, l = tid & 63, w = tid >> 6;
    const int rg = blockIdx.x*2 + w;
    const int m0 = rg*16;
    const int y = blockIdx.y;
    const unsigned short* Bf = Wf + (size_t)(4*y)*KCE*512 + l*8;
    const unsigned short* Ax = srcfrag + ((size_t)t*8 + rg)*2*512 + l*8;
    const unsigned short* Ah = hin + (size_t)rg*32*512 + l*8;
    floatx4 acc0={0,0,0,0}, acc1={0,0,0,0}, acc2={0,0,0,0}, acc3={0,0,0,0};

    #pragma unroll
    for (int kc = 0; kc < 2; kc++){
        short8 a  = *(const short8*)(Ax + kc*512);
        short8 b0 = *(const short8*)(Bf + (0*KCE + kc)*512);
        short8 b1 = *(const short8*)(Bf + (1*KCE + kc)*512);
        short8 b2 = *(const short8*)(Bf + (2*KCE + kc)*512);
        short8 b3 = *(const short8*)(Bf + (3*KCE + kc)*512);
        acc0 = __builtin_amdgcn_mfma_f32_16x16x32_bf16(a, b0, acc0, 0, 0, 0);
        acc1 = __builtin_amdgcn_mfma_f32_16x16x32_bf16(a, b1, acc1, 0, 0, 0);
        acc2 = __builtin_amdgcn_mfma_f32_16x16x32_bf16(a, b2, acc2, 0, 0, 0);
        acc3 = __builtin_amdgcn_mfma_f32_16x16x32_bf16(a, b3, acc3, 0, 0, 0);
    }
    #pragma unroll 4
    for (int kc = 0; kc < 32; kc++){
        short8 a  = *(const short8*)(Ah + kc*512);
        short8 b0 = *(const short8*)(Bf + (0*KCE + kc + 2)*512);
        short8 b1 = *(const short8*)(Bf + (1*KCE + kc + 2)*512);
        short8 b2 = *(const short8*)(Bf + (2*KCE + kc + 2)*512);
        short8 b3 = *(const short8*)(Bf + (3*KCE + kc + 2)*512);
        acc0 = __builtin_amdgcn_mfma_f32_16x16x32_bf16(a, b0, acc0, 0, 0, 0);
        acc1 = __builtin_amdgcn_mfma_f32_16x16x32_bf16(a, b1, acc1, 0, 0, 0);
        acc2 = __builtin_amdgcn_mfma_f32_16x16x32_bf16(a, b2, acc2, 0, 0, 0);
        acc3 = __builtin_amdgcn_mfma_f32_16x16x32_bf16(a, b3, acc3, 0, 0, 0);
    }

    const int col = l & 15, q = l >> 4;
    const int u = y*16 + col;
    const float bi  = bc[y*64 + col];
    const float bf_ = bc[y*64 + 16 + col];
    const float bg  = bc[y*64 + 32 + col];
    const float bo  = bc[y*64 + 48 + col];
    const int lsh = ((u >> 3) & 3) * 16;
    #pragma unroll
    for (int r = 0; r < 4; r++){
        const int m = m0 + q*4 + r;
        float gi = acc0[r] + bi;
        float gf = acc1[r] + bf_;
        float gg = acc2[r] + bg;
        float go = acc3[r] + bo;
        float co = cbuf[(size_t)m*Hn + u];
        float cn = sigmoidf_(gf)*co + sigmoidf_(gi)*tanhf(gg);
        float hv = sigmoidf_(go)*tanhf(cn);
        cbuf[(size_t)m*Hn + u] = cn;
        unsigned short hb = f2bf(hv);
        const int lanep = (q*4 + r) + lsh;
        hout[(((size_t)rg*32 + (u >> 5))*64 + lanep)*8 + (u & 7)] = hb;
        enco[((size_t)m*Sn + t)*Hn + u] = hb;
        if (last) adec0[(((size_t)rg*KCD + 32 + (u >> 5))*64 + lanep)*8 + (u & 7)] = hb;
    }
}

// ===================== decoder LSTM step ===================================
__global__ __launch_bounds__(128)
void dec_step(const unsigned short* __restrict__ Ac,       // [8][KCD][512]
              const unsigned short* __restrict__ Wf,       // [256][KCD][512]
              const float* __restrict__ bc, float* __restrict__ cbuf,
              unsigned short* __restrict__ An,             // next A: h slot
              unsigned short* __restrict__ hrow)           // row-major h for fc
{
    const int tid = threadIdx.x, l = tid & 63, w = tid >> 6;
    const int rg = blockIdx.x*2 + w;
    const int m0 = rg*16;
    const int y = blockIdx.y;
    const unsigned short* Bf = Wf + (size_t)(4*y)*KCD*512 + l*8;
    const unsigned short* Af = Ac + (size_t)rg*KCD*512 + l*8;
    floatx4 acc0={0,0,0,0}, acc1={0,0,0,0}, acc2={0,0,0,0}, acc3={0,0,0,0};

    #pragma unroll 4
    for (int kc = 0; kc < KCD; kc++){
        short8 a  = *(const short8*)(Af + kc*512);
        short8 b0 = *(const short8*)(Bf + (0*KCD + kc)*512);
        short8 b1 = *(const short8*)(Bf + (1*KCD + kc)*512);
        short8 b2 = *(const short8*)(Bf + (2*KCD + kc)*512);
        short8 b3 = *(const short8*)(Bf + (3*KCD + kc)*512);
        acc0 = __builtin_amdgcn_mfma_f32_16x16x32_bf16(a, b0, acc0, 0, 0, 0);
        acc1 = __builtin_amdgcn_mfma_f32_16x16x32_bf16(a, b1, acc1, 0, 0, 0);
        acc2 = __builtin_amdgcn_mfma_f32_16x16x32_bf16(a, b2, acc2, 0, 0, 0);
        acc3 = __builtin_amdgcn_mfma_f32_16x16x32_bf16(a, b3, acc3, 0, 0, 0);
    }

    const int col = l & 15, q = l >> 4;
    const int u = y*16 + col;
    const float bi  = bc[y*64 + col];
    const float bf_ = bc[y*64 + 16 + col];
    const float bg  = bc[y*64 + 32 + col];
    const float bo  = bc[y*64 + 48 + col];
    const int lsh = ((u >> 3) & 3) * 16;
    #pragma unroll
    for (int r = 0; r < 4; r++){
        const int m = m0 + q*4 + r;
        float gi = acc0[r] + bi;
        float gf = acc1[r] + bf_;
        float gg = acc2[r] + bg;
        float go = acc3[r] + bo;
        float co = cbuf[(size_t)m*Hn + u];
        float cn = sigmoidf_(gf)*co + sigmoidf_(gi)*tanhf(gg);
        float hv = sigmoidf_(go)*tanhf(cn);
        cbuf[(size_t)m*Hn + u] = cn;
        unsigned short hb = f2bf(hv);
        const int lanep = (q*4 + r) + lsh;
        An[(((size_t)rg*KCD + 32 + (u >> 5))*64 + lanep)*8 + (u & 7)] = hb;
        hrow[(size_t)m*Hn + u] = hb;
    }
}

// ===================== attention query GEMM ================================
// grid (4, 64), block 128. A = h part of Adec (chunks 32..63). One subtile/block-y.
__global__ __launch_bounds__(128)
void attnq_step(const unsigned short* __restrict__ Ac, const unsigned short* __restrict__ Wf,
                unsigned short* __restrict__ qout)
{
    const int tid = threadIdx.x, l = tid & 63, w = tid >> 6;
    const int rg = blockIdx.x*2 + w;
    const int m0 = rg*16;
    const int y = blockIdx.y;
    const unsigned short* Bf = Wf + (size_t)y*KCQ*512 + l*8;
    const unsigned short* Af = Ac + ((size_t)rg*KCD + 32)*512 + l*8;
    floatx4 acc = {0,0,0,0};
    #pragma unroll 8
    for (int kc = 0; kc < KCQ; kc++){
        short8 a = *(const short8*)(Af + kc*512);
        short8 b = *(const short8*)(Bf + kc*512);
        acc = __builtin_amdgcn_mfma_f32_16x16x32_bf16(a, b, acc, 0, 0, 0);
    }
    const int col = l & 15, q = l >> 4;
    #pragma unroll
    for (int r = 0; r < 4; r++){
        const int m = m0 + q*4 + r;
        qout[(size_t)m*Hn + y*16 + col] = f2bf(acc[r]);
    }
}

// ===================== attention: energies =================================
__global__ __launch_bounds__(256)
void energy_kernel(const unsigned short* __restrict__ q, const unsigned short* __restrict__ enc,
                   float* __restrict__ energy){
    int b = blockIdx.x;
    int wv = threadIdx.x >> 6, l = threadIdx.x & 63;
    int s = blockIdx.y*4 + wv;
    const uint4* qp = (const uint4*)(q + (size_t)b*Hn);
    const uint4* ep = (const uint4*)(enc + ((size_t)b*Sn + s)*Hn);
    float acc = 0.0f;
    #pragma unroll
    for (int i = 0; i < 2; i++){
        uint4 qv = qp[l + i*64];
        uint4 ev = ep[l + i*64];
        acc += bflo(qv.x)*bflo(ev.x) + bfhi(qv.x)*bfhi(ev.x);
        acc += bflo(qv.y)*bflo(ev.y) + bfhi(qv.y)*bfhi(ev.y);
        acc += bflo(qv.z)*bflo(ev.z) + bfhi(qv.z)*bfhi(ev.z);
        acc += bflo(qv.w)*bflo(ev.w) + bfhi(qv.w)*bfhi(ev.w);
    }
    #pragma unroll
    for (int off = 32; off; off >>= 1) acc += __shfl_down(acc, off);
    if (l == 0) energy[b*Sn + s] = acc;
}

// ===================== softmax + ctx (writes fragment slots) ===============
__global__ __launch_bounds__(256)
void softmax_ctx_kernel(const float* __restrict__ energy, const unsigned short* __restrict__ enc,
                        unsigned short* __restrict__ Afrag /* ctx chunks 0..31 */){
    __shared__ float wsm[Sn];
    __shared__ float red[256];
    int b = blockIdx.x, tid = threadIdx.x;
    float m = -1e30f;
    for (int s = tid; s < Sn; s += 256){ float e = energy[b*Sn + s]; wsm[s] = e; m = fmaxf(m, e); }
    red[tid] = m; __syncthreads();
    for (int o = 128; o; o >>= 1){ if (tid < o) red[tid] = fmaxf(red[tid], red[tid+o]); __syncthreads(); }
    m = red[0]; __syncthreads();
    float sum = 0.0f;
    for (int s = tid; s < Sn; s += 256){ float e = expf(wsm[s] - m); wsm[s] = e; sum += e; }
    red[tid] = sum; __syncthreads();
    for (int o = 128; o; o >>= 1){ if (tid < o) red[tid] += red[tid+o]; __syncthreads(); }
    float inv = 1.0f / red[0];
    float a0=0,a1=0,a2=0,a3=0;
    const uint2* base = (const uint2*)(enc + (size_t)b*Sn*Hn) + tid;
    #pragma unroll 8
    for (int s = 0; s < Sn; s++){
        float wv = wsm[s] * inv;
        uint2 v = base[(size_t)s*256];
        a0 += wv*bflo(v.x); a1 += wv*bfhi(v.x);
        a2 += wv*bflo(v.y); a3 += wv*bfhi(v.y);
    }
    // ctx units j0..j0+3 (k = j0): fragment store, 8B aligned
    const int j0 = tid*4;
    const int kc = j0 >> 5;
    const int lanep = (b & 15) + ((j0 >> 3) & 3)*16;
    ushort4 cv; cv.x = f2bf(a0); cv.y = f2bf(a1); cv.z = f2bf(a2); cv.w = f2bf(a3);
    *(ushort4*)(Afrag + ((((size_t)(b >> 4))*KCD + kc)*64 + lanep)*8 + (j0 & 7)) = cv;
}

// ===================== fc head + feedback ==================================
__global__ __launch_bounds__(256)
void fc_out_kernel(const unsigned short* __restrict__ h, const float* __restrict__ fcW,
                   const float* __restrict__ fcb, float* __restrict__ out,
                   unsigned short* __restrict__ An /* prev_y slot */, int d){
    __shared__ float red[256];
    int b = blockIdx.x, tid = threadIdx.x;
    uint2 v = ((const uint2*)(h + (size_t)b*Hn))[tid];
    float acc = fcW[tid*4+0]*bflo(v.x) + fcW[tid*4+1]*bfhi(v.x)
              + fcW[tid*4+2]*bflo(v.y) + fcW[tid*4+3]*bfhi(v.y);
    red[tid] = acc; __syncthreads();
    for (int o = 128; o; o >>= 1){ if (tid < o) red[tid] += red[tid+o]; __syncthreads(); }
    if (tid == 0){
        float p = red[0] + fcb[0];
        out[b*Tn + d] = p;
        // prev_y at k=2048: kc=64, lane=(b&15), j=0
        An[(((size_t)(b >> 4))*KCD + 64)*512 + (b & 15)*8] = f2bf(p);
    }
}

extern "C" void kernel_launch(void* const* d_in, const int* in_sizes, int n_in,
                              void* d_out, int out_size, void* d_ws, size_t ws_size,
                              hipStream_t stream){
    const float* src  = (const float*)d_in[0];
    const float* eWih = (const float*)d_in[1];
    const float* eWhh = (const float*)d_in[2];
    const float* ebih = (const float*)d_in[3];
    const float* ebhh = (const float*)d_in[4];
    const float* dWih = (const float*)d_in[5];
    const float* dWhh = (const float*)d_in[6];
    const float* dbih = (const float*)d_in[7];
    const float* dbhh = (const float*)d_in[8];
    const float* attnW= (const float*)d_in[9];
    const float* fcW  = (const float*)d_in[10];
    const float* fcb  = (const float*)d_in[11];
    float* out = (float*)d_out;

    char* base = (char*)d_ws;
    auto alloc = [&](size_t bytes){ void* p = base; base += (bytes + 255) & ~255ull; return p; };
    unsigned short* Wencf = (unsigned short*)alloc((size_t)256*KCE*512*2);
    float*          benc  = (float*)alloc(G4*4);
    unsigned short* Wdecf = (unsigned short*)alloc((size_t)256*KCD*512*2);
    float*          bdec  = (float*)alloc(G4*4);
    unsigned short* Wattf = (unsigned short*)alloc((size_t)64*KCQ*512*2);
    unsigned short* srcf  = (unsigned short*)alloc((size_t)Sn*8*2*512*2);
    unsigned short* enco  = (unsigned short*)alloc((size_t)Bn*Sn*Hn*2);
    unsigned short* hf0   = (unsigned short*)alloc((size_t)8*32*512*2);
    unsigned short* hf1   = (unsigned short*)alloc((size_t)8*32*512*2);
    float*          cbuf  = (float*)alloc((size_t)Bn*Hn*4);
    unsigned short* A0f   = (unsigned short*)alloc((size_t)8*KCD*512*2);
    unsigned short* A1f   = (unsigned short*)alloc((size_t)8*KCD*512*2);
    unsigned short* qbf   = (unsigned short*)alloc((size_t)Bn*Hn*2);
    unsigned short* hrow  = (unsigned short*)alloc((size_t)Bn*Hn*2);
    float*          ener  = (float*)alloc((size_t)Bn*Sn*4);

    conv_srcf<<<2048, 256, 0, stream>>>(src, srcf);
    pack_encf<<<4096, 256, 0, stream>>>(eWih, eWhh, ebih, ebhh, Wencf, benc);
    pack_decf<<<8192, 256, 0, stream>>>(dWih, dWhh, dbih, dbhh, Wdecf, bdec);
    pack_attnf<<<1024, 256, 0, stream>>>(attnW, Wattf);
    init_ws<<<1040, 256, 0, stream>>>(hf0, cbuf, A0f, A1f);

    unsigned short* hf[2] = {hf0, hf1};
    unsigned short* Ad[2] = {A0f, A1f};
    dim3 gg(4, 64);

    for (int t = 0; t < Sn; t++){
        enc_step<<<gg, 128, 0, stream>>>(srcf, hf[t&1], Wencf, benc, cbuf,
                                         hf[(t+1)&1], enco, A0f, t, t == Sn-1);
    }
    for (int d = 0; d < Tn; d++){
        unsigned short* Ac = Ad[d&1];
        unsigned short* An = Ad[(d+1)&1];
        attnq_step<<<gg, 128, 0, stream>>>(Ac, Wattf, qbf);
        energy_kernel<<<dim3(Bn, 84), 256, 0, stream>>>(qbf, enco, ener);
        softmax_ctx_kernel<<<Bn, 256, 0, stream>>>(ener, enco, Ac);
        dec_step<<<gg, 128, 0, stream>>>(Ac, Wdecf, bdec, cbuf, An, hrow);
        fc_out_kernel<<<Bn, 256, 0, stream>>>(hrow, fcW, fcb, out, An, d);
    }
}